// Round 7
// baseline (133.949 us; speedup 1.0000x reference)
//
#include <hip/hip_runtime.h>

#define D 64
#define ITEM_PAD 100000
#define NROWS_I (ITEM_PAD + 1)
#define LSEQ 200
#define BATCH 4096
#define NEG_W 0.1f
#define NBI 512                         // gram_item partial blocks
#define NBU 64                          // gram_user partial blocks
#define GSZ (D * D)                     // 4096
#define TSTRIDE 40                      // LDS transpose stride (32 k + 8 pad), ushorts

// ws layout (floats):
#define PITEM_OFF 0
#define PUSER_OFF ((size_t)NBI * GSZ)              // 2,097,152
#define POS_OFF   (PUSER_OFF + (size_t)NBU * GSZ)  // 2,359,296
#define WS3_OFF   (POS_OFF + BATCH)                // 2,363,392
#define CTR_OFF   (WS3_OFF + 256)

typedef __attribute__((ext_vector_type(8))) short short8;   // 8 bf16 (4 VGPRs)
typedef __attribute__((ext_vector_type(4))) float f32x4;

__device__ __forceinline__ unsigned short f2bf_rne(float x) {
    unsigned u = __builtin_bit_cast(unsigned, x);
    return (unsigned short)((u + 0x7fffu + ((u >> 16) & 1u)) >> 16);
}

// ---------------------------------------------------------------------------
// Kernel A: gram partials (MFMA bf16) + pos-loss partials, ONE launch.
//   blocks [0, NBI)          : item-Gram partial -> Pitem[blk]
//   blocks [NBI, NBI+NBU)    : user-Gram partial (gather via uids)
//   blocks [NBI+NBU, +BATCH) : pos-loss row partial (fp32 item_W gather)
// Gram: per 32-row chunk, stage bf16 TRANSPOSED in LDS (Wt[col][k], stride 40
// ushorts). Frag for colbase cb: lane reads Wt[cb + (lane&15)][ (lane>>4)*8 ..+8 ]
// = one b128. Wave w computes C rows [w*16, w*16+16): A=frag(w*16),
// B=frag(q*16) for q=0..3, acc in fp32. C/D: row=(lane>>4)*4+reg, col=lane&15.
// Gram symmetry makes the result robust to a C row/col swap.
// ---------------------------------------------------------------------------
__global__ void fused_all(const int* __restrict__ uids,
                          const int* __restrict__ pos_iids,
                          const float* __restrict__ user_W,
                          const float* __restrict__ item_W,
                          const float* __restrict__ h,
                          float* __restrict__ ws) {
    __shared__ unsigned short WtS[64 * TSTRIDE];   // 5120 B, aliased by pos path
    const int bid  = blockIdx.x;
    const int t    = threadIdx.x;
    const int lane = t & 63;
    const int wave = t >> 6;

    if (bid == 0 && t == 0) ((unsigned*)(ws + CTR_OFF))[0] = 0u;

    if (bid < NBI + NBU) {
        // ---------------- Gram partial via MFMA ----------------
        const bool item = (bid < NBI);
        const float* __restrict__ W = item ? item_W : user_W;
        const int nrows  = item ? NROWS_I : BATCH;
        const int stride = item ? NBI : NBU;
        const int b0     = item ? bid : bid - NBI;
        float* __restrict__ out =
            ws + (item ? PITEM_OFF + (size_t)b0 * GSZ : PUSER_OFF + (size_t)b0 * GSZ);

        const int rloc = t & 31;          // row within chunk
        const int c0   = (t >> 5) * 8;    // 8-col group
        const int m    = lane & 15;
        const int g    = lane >> 4;

        f32x4 acc[4] = {{0.f,0.f,0.f,0.f},{0.f,0.f,0.f,0.f},
                        {0.f,0.f,0.f,0.f},{0.f,0.f,0.f,0.f}};

        const int nchunks = (nrows + 31) >> 5;

        // prefetch first chunk (8 floats/thread)
        float4 pa = make_float4(0.f,0.f,0.f,0.f), pb = pa;
        int c = b0;
        if (c < nchunks) {
            const int r = (c << 5) + rloc;
            if (r < nrows) {
                const int src = item ? r : uids[r];
                pa = *(const float4*)(W + (size_t)src * D + c0);
                pb = *(const float4*)(W + (size_t)src * D + c0 + 4);
            }
        }

        while (c < nchunks) {
            unsigned short hb[8];
            hb[0]=f2bf_rne(pa.x); hb[1]=f2bf_rne(pa.y); hb[2]=f2bf_rne(pa.z); hb[3]=f2bf_rne(pa.w);
            hb[4]=f2bf_rne(pb.x); hb[5]=f2bf_rne(pb.y); hb[6]=f2bf_rne(pb.z); hb[7]=f2bf_rne(pb.w);

            __syncthreads();   // previous chunk's frag reads complete
            #pragma unroll
            for (int j = 0; j < 8; ++j)
                WtS[(c0 + j) * TSTRIDE + rloc] = hb[j];   // transposed store
            __syncthreads();

            // prefetch next chunk before MFMA
            const int cn = c + stride;
            pa = make_float4(0.f,0.f,0.f,0.f); pb = pa;
            if (cn < nchunks) {
                const int r = (cn << 5) + rloc;
                if (r < nrows) {
                    const int src = item ? r : uids[r];
                    pa = *(const float4*)(W + (size_t)src * D + c0);
                    pb = *(const float4*)(W + (size_t)src * D + c0 + 4);
                }
            }

            // frags: colbase q*16; A = frag[wave], B = frag[q]
            short8 frag[4];
            #pragma unroll
            for (int q = 0; q < 4; ++q)
                frag[q] = *(const short8*)(&WtS[(q * 16 + m) * TSTRIDE + g * 8]);
            #pragma unroll
            for (int q = 0; q < 4; ++q)
                acc[q] = __builtin_amdgcn_mfma_f32_16x16x32_bf16(frag[wave], frag[q],
                                                                 acc[q], 0, 0, 0);
            c = cn;
        }

        // store: C row = wave*16 + g*4 + reg, col = q*16 + m
        #pragma unroll
        for (int q = 0; q < 4; ++q)
            #pragma unroll
            for (int reg = 0; reg < 4; ++reg)
                out[(wave * 16 + g * 4 + reg) * D + q * 16 + m] = acc[q][reg];
    } else {
        // ---------------- pos-loss row partial (fp32 gather) ----------------
        const int b = bid - (NBI + NBU);
        float* uh   = (float*)WtS;              // [64]
        int*   sidx = (int*)WtS + 64;           // [200]
        float* red  = (float*)WtS + 264;        // [4]

        if (t < LSEQ) sidx[t] = pos_iids[(size_t)b * LSEQ + t];
        if (t >= 192) {
            const int j = t - 192;
            uh[j] = user_W[(size_t)uids[b] * D + j] * h[j];
        }
        __syncthreads();

        const int p    = lane >> 4;      // 0..3
        const int q    = lane & 15;      // 0..15
        const int base = wave * 4 + p;   // 0..15

        const float4 u4 = *(const float4*)(uh + q * 4);

        int ids[13];
        #pragma unroll
        for (int k = 0; k < 13; ++k) {
            const int l = base + 16 * k;
            ids[k] = (l < LSEQ) ? sidx[l] : ITEM_PAD;
        }
        float4 rows[13];
        #pragma unroll
        for (int k = 0; k < 13; ++k) {
            float4 v = make_float4(0.f, 0.f, 0.f, 0.f);
            if (ids[k] != ITEM_PAD)
                v = *(const float4*)(item_W + (size_t)ids[k] * D + q * 4);
            rows[k] = v;
        }

        float local = 0.f;
        #pragma unroll
        for (int k = 0; k < 13; ++k) {
            float s = u4.x*rows[k].x + u4.y*rows[k].y + u4.z*rows[k].z + u4.w*rows[k].w;
            s += __shfl_xor(s, 1);
            s += __shfl_xor(s, 2);
            s += __shfl_xor(s, 4);
            s += __shfl_xor(s, 8);
            if (q == 0)
                local += (1.0f - NEG_W) * s * s - 2.0f * s;   // s==0 masked/oob
        }
        local += __shfl_xor(local, 1);
        local += __shfl_xor(local, 2);
        local += __shfl_xor(local, 4);
        local += __shfl_xor(local, 8);
        local += __shfl_xor(local, 16);
        local += __shfl_xor(local, 32);
        if (lane == 0) red[wave] = local;
        __syncthreads();
        if (t == 0)
            ws[POS_OFF + b] = red[0] + red[1] + red[2] + red[3];
    }
}

// ---------------------------------------------------------------------------
// Kernel B: 256 blocks. Block bb: Gi/Gu reduce for k-slice [bb*16,+16), apply
// NEG_W*h_i*h_j, add pos slice -> ws3[bb]; last block sums ws3 -> out[0].
// ---------------------------------------------------------------------------
__global__ void reduce_final(const float* __restrict__ ws,
                             const float* __restrict__ h,
                             float* __restrict__ ws3,
                             unsigned* __restrict__ counter,
                             float* __restrict__ out) {
    __shared__ float rI[4][16];
    __shared__ float rU[4][16];
    __shared__ int isLast;
    const int bb = blockIdx.x;
    const int t  = threadIdx.x;
    const int kk = t & 15;
    const int ps = t >> 4;        // 0..15
    const int lane = t & 63;
    const int wave = t >> 6;
    const int k  = bb * 16 + kk;

    float si = 0.f, su = 0.f;
    #pragma unroll 8
    for (int p = ps; p < NBI; p += 16) si += ws[PITEM_OFF + (size_t)p * GSZ + k];
    #pragma unroll
    for (int p = ps; p < NBU; p += 16) su += ws[PUSER_OFF + (size_t)p * GSZ + k];

    si += __shfl_xor(si, 16); si += __shfl_xor(si, 32);
    su += __shfl_xor(su, 16); su += __shfl_xor(su, 32);
    if (lane < 16) { rI[wave][kk] = si; rU[wave][kk] = su; }
    __syncthreads();

    if (wave == 0) {
        float c = 0.f;
        if (t < 16) {
            const float Gi = rI[0][t] + rI[1][t] + rI[2][t] + rI[3][t];
            const float Gu = rU[0][t] + rU[1][t] + rU[2][t] + rU[3][t];
            const int kg = bb * 16 + t;
            const int i = kg >> 6, j = kg & 63;
            c = NEG_W * Gi * Gu * h[i] * h[j] + ws[POS_OFF + bb * 16 + t];
        }
        c += __shfl_xor(c, 1);
        c += __shfl_xor(c, 2);
        c += __shfl_xor(c, 4);
        c += __shfl_xor(c, 8);
        if (lane == 0) ws3[bb] = c;
    }

    if (t == 0) {
        __threadfence();
        isLast = (atomicAdd(counter, 1u) == 255u);
    }
    __syncthreads();
    if (isLast) {
        __threadfence();
        float s = ws3[t];
        s += __shfl_xor(s, 1);
        s += __shfl_xor(s, 2);
        s += __shfl_xor(s, 4);
        s += __shfl_xor(s, 8);
        s += __shfl_xor(s, 16);
        s += __shfl_xor(s, 32);
        __shared__ float red[4];
        if (lane == 0) red[wave] = s;
        __syncthreads();
        if (t == 0) out[0] = red[0] + red[1] + red[2] + red[3];
    }
}

extern "C" void kernel_launch(void* const* d_in, const int* in_sizes, int n_in,
                              void* d_out, int out_size, void* d_ws, size_t ws_size,
                              hipStream_t stream) {
    const int*   uids     = (const int*)d_in[0];
    const int*   pos_iids = (const int*)d_in[1];
    const float* user_W   = (const float*)d_in[2];
    const float* item_W   = (const float*)d_in[3];
    const float* h        = (const float*)d_in[4];
    float* out = (float*)d_out;
    float* ws  = (float*)d_ws;

    fused_all<<<NBI + NBU + BATCH, 256, 0, stream>>>(uids, pos_iids, user_W,
                                                     item_W, h, ws);
    reduce_final<<<256, 256, 0, stream>>>(ws, h, ws + WS3_OFF,
                                          (unsigned*)(ws + CTR_OFF), out);
}

// Round 8
// 124.231 us; speedup vs baseline: 1.0782x; 1.0782x over previous
//
#include <hip/hip_runtime.h>

#define D 64
#define ITEM_PAD 100000
#define NROWS_I (ITEM_PAD + 1)
#define LSEQ 200
#define BATCH 4096
#define NEG_W 0.1f
#define NBI 512                         // gram_item partial blocks
#define NBU 64                          // gram_user partial blocks
#define GSZ (D * D)                     // 4096

// ws layout (floats):
#define TAB_FLOATS 1600064              // fp8 table: 100001 rows x 64 fp8 (6.4 MB)
#define PITEM_OFF  ((size_t)TAB_FLOATS)
#define PUSER_OFF  (PITEM_OFF + (size_t)NBI * GSZ)
#define POS_OFF    (PUSER_OFF + (size_t)NBU * GSZ)
#define WS3_OFF    (POS_OFF + BATCH)
#define CTR_OFF    (WS3_OFF + 256)

// decode 4 fp8 (one packed uint) -> 4 floats
__device__ __forceinline__ void fp8x4_dec(unsigned w, float* o) {
    auto lo = __builtin_amdgcn_cvt_pk_f32_fp8((int)w, false);
    auto hi = __builtin_amdgcn_cvt_pk_f32_fp8((int)w, true);
    o[0] = lo[0]; o[1] = lo[1]; o[2] = hi[0]; o[3] = hi[1];
}

// ---------------------------------------------------------------------------
// K1: item_W fp32 -> fp8 e4m3 table (value*8, descale folded downstream).
// Each thread converts 8 floats -> uint2. Also zero-inits the K3 counter.
// ---------------------------------------------------------------------------
__global__ void convert_fp8(const float* __restrict__ item_W,
                            float* __restrict__ ws) {
    if (blockIdx.x == 0 && threadIdx.x == 0)
        ((unsigned*)(ws + CTR_OFF))[0] = 0u;
    unsigned* __restrict__ tab = (unsigned*)ws;
    const long long n8 = (long long)NROWS_I * 8;   // 800008 uint2 units
    const long long stride = (long long)gridDim.x * 256;
    for (long long i = (long long)blockIdx.x * 256 + threadIdx.x; i < n8; i += stride) {
        const float4 a = *(const float4*)(item_W + i * 8);
        const float4 b = *(const float4*)(item_W + i * 8 + 4);
        int lo = 0, hi = 0;
        lo = __builtin_amdgcn_cvt_pk_fp8_f32(a.x * 8.f, a.y * 8.f, lo, false);
        lo = __builtin_amdgcn_cvt_pk_fp8_f32(a.z * 8.f, a.w * 8.f, lo, true);
        hi = __builtin_amdgcn_cvt_pk_fp8_f32(b.x * 8.f, b.y * 8.f, hi, false);
        hi = __builtin_amdgcn_cvt_pk_fp8_f32(b.z * 8.f, b.w * 8.f, hi, true);
        uint2 v; v.x = (unsigned)lo; v.y = (unsigned)hi;
        *(uint2*)(tab + i * 2) = v;
    }
}

// ---------------------------------------------------------------------------
// K2: gram partials + pos-loss partials, concurrent in one launch.
//   blocks [0, NBI)          : item-Gram partial from fp8 table (x0.125 decode)
//   blocks [NBI, NBI+NBU)    : user-Gram partial (fp32 gather via uids)
//   blocks [NBI+NBU, +BATCH) : pos-loss row partial from fp8 table
// ---------------------------------------------------------------------------
__global__ void gram_pos(const int* __restrict__ uids,
                         const int* __restrict__ pos_iids,
                         const float* __restrict__ user_W,
                         const float* __restrict__ h,
                         float* __restrict__ ws) {
    __shared__ float smem[32 * D];   // 8 KB
    const int bid  = blockIdx.x;
    const int t    = threadIdx.x;
    const int lane = t & 63;
    const int wave = t >> 6;

    if (bid < NBI + NBU) {
        const bool item = (bid < NBI);
        const int nrows  = item ? NROWS_I : BATCH;
        const int stride = item ? NBI : NBU;
        const int b0     = item ? bid : bid - NBI;
        float* __restrict__ out =
            ws + (item ? PITEM_OFF + (size_t)b0 * GSZ : PUSER_OFF + (size_t)b0 * GSZ);
        const unsigned* __restrict__ tab = (const unsigned*)ws;

        const int ti = t >> 4, tj = t & 15;      // compute mapping (4x4 tile)
        const int si = t >> 3, sj = t & 7;       // item staging: 32 rows x 8 uint2
        float acc[4][4] = {{0.f,0.f,0.f,0.f},{0.f,0.f,0.f,0.f},
                           {0.f,0.f,0.f,0.f},{0.f,0.f,0.f,0.f}};
        const int nchunks = (nrows + 31) >> 5;

        // prefetch first chunk
        uint2  pi = make_uint2(0u, 0u);
        float4 va = make_float4(0.f,0.f,0.f,0.f), vb = va;
        int c = b0;
        if (c < nchunks) {
            if (item) {
                const int r = (c << 5) + si;
                if (r < nrows) pi = *(const uint2*)(tab + ((size_t)r * 8 + sj) * 2);
            } else {
                const int ra = (c << 5) + ti, rb = ra + 16;
                if (ra < nrows) va = *(const float4*)(user_W + (size_t)uids[ra] * D + tj * 4);
                if (rb < nrows) vb = *(const float4*)(user_W + (size_t)uids[rb] * D + tj * 4);
            }
        }

        while (c < nchunks) {
            __syncthreads();
            if (item) {
                float f[8];
                fp8x4_dec(pi.x, f);
                fp8x4_dec(pi.y, f + 4);
                float4 o0 = make_float4(f[0]*0.125f, f[1]*0.125f, f[2]*0.125f, f[3]*0.125f);
                float4 o1 = make_float4(f[4]*0.125f, f[5]*0.125f, f[6]*0.125f, f[7]*0.125f);
                *(float4*)(smem + si * D + sj * 8)     = o0;
                *(float4*)(smem + si * D + sj * 8 + 4) = o1;
            } else {
                *(float4*)(smem + ti * D + tj * 4)        = va;
                *(float4*)(smem + (ti + 16) * D + tj * 4) = vb;
            }
            __syncthreads();

            const int cn = c + stride;
            pi = make_uint2(0u, 0u);
            va = make_float4(0.f,0.f,0.f,0.f); vb = va;
            if (cn < nchunks) {
                if (item) {
                    const int r = (cn << 5) + si;
                    if (r < nrows) pi = *(const uint2*)(tab + ((size_t)r * 8 + sj) * 2);
                } else {
                    const int ra = (cn << 5) + ti, rb = ra + 16;
                    if (ra < nrows) va = *(const float4*)(user_W + (size_t)uids[ra] * D + tj * 4);
                    if (rb < nrows) vb = *(const float4*)(user_W + (size_t)uids[rb] * D + tj * 4);
                }
            }

            #pragma unroll
            for (int r2 = 0; r2 < 32; ++r2) {
                float xi[4], xj[4];
                *(float4*)xi = *(const float4*)(smem + r2 * D + ti * 4);
                *(float4*)xj = *(const float4*)(smem + r2 * D + tj * 4);
                #pragma unroll
                for (int a = 0; a < 4; ++a)
                    #pragma unroll
                    for (int b2 = 0; b2 < 4; ++b2)
                        acc[a][b2] += xi[a] * xj[b2];
            }
            c = cn;
        }
        #pragma unroll
        for (int a = 0; a < 4; ++a)
            *(float4*)(out + (ti * 4 + a) * D + tj * 4) = *(const float4*)acc[a];
    } else {
        // ---- pos-loss partial from fp8 table ----
        __shared__ float uh[D];
        __shared__ int   sidx[LSEQ];
        __shared__ float red[4];
        const int b = bid - (NBI + NBU);
        const uint2* __restrict__ tab = (const uint2*)ws;

        if (t < LSEQ) sidx[t] = pos_iids[(size_t)b * LSEQ + t];
        if (t >= 192) {
            const int j = t - 192;
            uh[j] = user_W[(size_t)uids[b] * D + j] * h[j] * 0.125f;  // descale
        }
        __syncthreads();

        const int p    = lane >> 3;      // 0..7 (row slot in wave)
        const int q    = lane & 7;       // 0..7 (8 d's per lane)
        const int base = wave * 8 + p;   // 0..31

        float u8[8];
        *(float4*)(u8 + 0) = *(const float4*)(uh + q * 8);
        *(float4*)(u8 + 4) = *(const float4*)(uh + q * 8 + 4);

        int ids[7];
        #pragma unroll
        for (int k = 0; k < 7; ++k) {
            const int l = base + 32 * k;
            ids[k] = (l < LSEQ) ? sidx[l] : ITEM_PAD;
        }
        uint2 rows[7];
        #pragma unroll
        for (int k = 0; k < 7; ++k) {
            uint2 v = make_uint2(0u, 0u);
            if (ids[k] != ITEM_PAD)
                v = tab[(size_t)ids[k] * 8 + q];
            rows[k] = v;
        }

        float local = 0.f;
        #pragma unroll
        for (int k = 0; k < 7; ++k) {
            float f[8];
            fp8x4_dec(rows[k].x, f);
            fp8x4_dec(rows[k].y, f + 4);
            float s = f[0]*u8[0] + f[1]*u8[1] + f[2]*u8[2] + f[3]*u8[3]
                    + f[4]*u8[4] + f[5]*u8[5] + f[6]*u8[6] + f[7]*u8[7];
            s += __shfl_xor(s, 1);
            s += __shfl_xor(s, 2);
            s += __shfl_xor(s, 4);
            if (q == 0)
                local += (1.0f - NEG_W) * s * s - 2.0f * s;   // s==0 for masked/oob
        }
        local += __shfl_xor(local, 1);
        local += __shfl_xor(local, 2);
        local += __shfl_xor(local, 4);
        local += __shfl_xor(local, 8);
        local += __shfl_xor(local, 16);
        local += __shfl_xor(local, 32);
        if (lane == 0) red[wave] = local;
        __syncthreads();
        if (t == 0)
            ws[POS_OFF + b] = red[0] + red[1] + red[2] + red[3];
    }
}

// ---------------------------------------------------------------------------
// K3: 256 blocks. Block bb: Gi/Gu reduce for k-slice [bb*16,+16), apply
// NEG_W*h_i*h_j, add pos slice -> ws3[bb]. Last block (device-scope counter
// + fences) sums ws3 -> out[0].
// ---------------------------------------------------------------------------
__global__ void reduce_final(const float* __restrict__ ws,
                             const float* __restrict__ h,
                             float* __restrict__ ws3,
                             unsigned* __restrict__ counter,
                             float* __restrict__ out) {
    __shared__ float rI[4][16];
    __shared__ float rU[4][16];
    __shared__ int isLast;
    const int bb = blockIdx.x;
    const int t  = threadIdx.x;
    const int kk = t & 15;
    const int ps = t >> 4;        // 0..15
    const int lane = t & 63;
    const int wave = t >> 6;
    const int k  = bb * 16 + kk;

    float si = 0.f, su = 0.f;
    #pragma unroll 8
    for (int p = ps; p < NBI; p += 16) si += ws[PITEM_OFF + (size_t)p * GSZ + k];
    #pragma unroll
    for (int p = ps; p < NBU; p += 16) su += ws[PUSER_OFF + (size_t)p * GSZ + k];

    si += __shfl_xor(si, 16); si += __shfl_xor(si, 32);
    su += __shfl_xor(su, 16); su += __shfl_xor(su, 32);
    if (lane < 16) { rI[wave][kk] = si; rU[wave][kk] = su; }
    __syncthreads();

    if (wave == 0) {
        float c = 0.f;
        if (t < 16) {
            const float Gi = rI[0][t] + rI[1][t] + rI[2][t] + rI[3][t];
            const float Gu = rU[0][t] + rU[1][t] + rU[2][t] + rU[3][t];
            const int kg = bb * 16 + t;
            const int i = kg >> 6, j = kg & 63;
            c = NEG_W * Gi * Gu * h[i] * h[j] + ws[POS_OFF + bb * 16 + t];
        }
        c += __shfl_xor(c, 1);
        c += __shfl_xor(c, 2);
        c += __shfl_xor(c, 4);
        c += __shfl_xor(c, 8);
        if (lane == 0) ws3[bb] = c;
    }

    if (t == 0) {
        __threadfence();
        isLast = (atomicAdd(counter, 1u) == 255u);
    }
    __syncthreads();
    if (isLast) {
        __threadfence();
        float s = ws3[t];
        s += __shfl_xor(s, 1);
        s += __shfl_xor(s, 2);
        s += __shfl_xor(s, 4);
        s += __shfl_xor(s, 8);
        s += __shfl_xor(s, 16);
        s += __shfl_xor(s, 32);
        __shared__ float red[4];
        if (lane == 0) red[wave] = s;
        __syncthreads();
        if (t == 0) out[0] = red[0] + red[1] + red[2] + red[3];
    }
}

extern "C" void kernel_launch(void* const* d_in, const int* in_sizes, int n_in,
                              void* d_out, int out_size, void* d_ws, size_t ws_size,
                              hipStream_t stream) {
    const int*   uids     = (const int*)d_in[0];
    const int*   pos_iids = (const int*)d_in[1];
    const float* user_W   = (const float*)d_in[2];
    const float* item_W   = (const float*)d_in[3];
    const float* h        = (const float*)d_in[4];
    float* out = (float*)d_out;
    float* ws  = (float*)d_ws;

    convert_fp8<<<1024, 256, 0, stream>>>(item_W, ws);
    gram_pos<<<NBI + NBU + BATCH, 256, 0, stream>>>(uids, pos_iids, user_W, h, ws);
    reduce_final<<<256, 256, 0, stream>>>(ws, h, ws + WS3_OFF,
                                          (unsigned*)(ws + CTR_OFF), out);
}